// Round 2
// baseline (24760.753 us; speedup 1.0000x reference)
//
#include <hip/hip_runtime.h>
#include <stdint.h>

#define TT 16384
#define DH 512
#define KK 128
#define SENT 0xAAAAAAAAu
#define CROWS 32
#define NCHUNK (TT / CROWS)   // 512
#define NPROJ 56
#define RSLOT 16

// Small cross-block state lives in device globals (ws budget stays at the
// proven 2*TT*DH floats). Re-initialized by init_kernel every launch.
__device__ uint32_t g_ring[2][RSLOT][DH];   // parity-tagged h exchange rings
__device__ uint32_t g_flagXp[2][NCHUNK];    // Xp chunk-ready flags (1 = ready)

static __device__ __forceinline__ uint32_t aload(const uint32_t* p) {
    return __hip_atomic_load(p, __ATOMIC_RELAXED, __HIP_MEMORY_SCOPE_AGENT);
}
static __device__ __forceinline__ void astore(uint32_t* p, uint32_t v) {
    __hip_atomic_store(p, v, __ATOMIC_RELAXED, __HIP_MEMORY_SCOPE_AGENT);
}
static __device__ __forceinline__ float aloadf(const float* p) {
    return __uint_as_float(aload((const uint32_t*)p));
}

__global__ void init_kernel() {
    const int tid = threadIdx.x;
    uint32_t* r = &g_ring[0][0][0];
    for (int i = tid; i < 2 * RSLOT * DH; i += 1024) r[i] = SENT;  // sign bit 1
    uint32_t* f = &g_flagXp[0][0];
    for (int i = tid; i < 2 * NCHUNK; i += 1024) f[i] = SENT;      // != 1
}

// ---------------- projector: 32-row chunk GEMM  dst = src @ W  ----------------
// srcMode 0: plain loads (X, pre-written).  srcMode 1: per-word sentinel poll
// (H0, written live by scan-0; in-place overwrite is safe: sole consumer is us,
// and the chunk is fully staged to LDS before any store).
static __device__ void proj_chunk(const float* __restrict__ W,
                                  const float* __restrict__ src, int srcMode,
                                  float* __restrict__ dst, uint32_t* flag, int t0,
                                  float* inT /* [DH][36] */, float* wt /* [32][516] */)
{
    const int tid = threadIdx.x;
    // stage input chunk transposed: inT[k][row]
    #pragma unroll
    for (int i = 0; i < 16; ++i) {
        int idx = tid + 1024 * i;            // 0..16383
        int row = idx >> 9;
        int col = idx & 511;
        float v;
        if (srcMode == 0) {
            v = src[(size_t)t0 * DH + idx];
        } else {
            const uint32_t* p = (const uint32_t*)src + (size_t)t0 * DH + idx;
            uint32_t u;
            while ((u = aload(p)) == SENT) __builtin_amdgcn_s_sleep(1);
            v = __uint_as_float(u);
        }
        inT[col * 36 + row] = v;
    }
    __syncthreads();

    const int rg = (tid >> 7) & 7;   // row group: rows 4rg..4rg+3
    const int cg = tid & 127;        // col group: cols 4cg..4cg+3
    float acc[4][4] = {{0.f}};

    for (int kt = 0; kt < 16; ++kt) {
        const int k0 = kt * 32;
        #pragma unroll
        for (int i = 0; i < 4; ++i) {                  // stage 32x512 W tile
            int f4 = tid + 1024 * i;                   // 0..4095 float4s
            int wr = f4 >> 7;
            int wc = (f4 & 127) << 2;
            *(float4*)&wt[wr * 516 + wc] =
                *(const float4*)&W[(size_t)(k0 + wr) * DH + wc];
        }
        __syncthreads();
        #pragma unroll 8
        for (int kk = 0; kk < 32; ++kk) {
            float4 a = *(const float4*)&inT[(k0 + kk) * 36 + (rg << 2)];
            float4 w = *(const float4*)&wt[kk * 516 + (cg << 2)];
            acc[0][0] += a.x * w.x; acc[0][1] += a.x * w.y; acc[0][2] += a.x * w.z; acc[0][3] += a.x * w.w;
            acc[1][0] += a.y * w.x; acc[1][1] += a.y * w.y; acc[1][2] += a.y * w.z; acc[1][3] += a.y * w.w;
            acc[2][0] += a.z * w.x; acc[2][1] += a.z * w.y; acc[2][2] += a.z * w.z; acc[2][3] += a.z * w.w;
            acc[3][0] += a.w * w.x; acc[3][1] += a.w * w.y; acc[3][2] += a.w * w.z; acc[3][3] += a.w * w.w;
        }
        __syncthreads();
    }
    #pragma unroll
    for (int i = 0; i < 4; ++i)
        #pragma unroll
        for (int j = 0; j < 4; ++j)
            astore((uint32_t*)&dst[(size_t)(t0 + (rg << 2) + i) * DH + (cg << 2) + j],
                   __float_as_uint(acc[i][j]));
    __threadfence();
    __syncthreads();
    if (tid == 0)
        __hip_atomic_store(flag, 1u, __ATOMIC_RELEASE, __HIP_MEMORY_SCOPE_AGENT);
}

// ---------------- fused persistent kernel ----------------
// grid = 64 x 1024.  Blocks with (b<32 && b%8<2): scan role, layer=b%8, slice=b>>3
// (b%8 swizzle: layer-0 scan blocks land on one XCD if dispatch is round-robin —
// perf heuristic only).  All other blocks: projectors for Xp0/Xp1.
__global__ __launch_bounds__(1024, 1)
void fused(const float* __restrict__ X,
           const float* __restrict__ Wx0, const float* __restrict__ Wh0,
           const float* __restrict__ bh0, const float* __restrict__ h00,
           const float* __restrict__ Wx1, const float* __restrict__ Wh1,
           const float* __restrict__ bh1, const float* __restrict__ h01,
           float* H0r, float* H1r)
{
    __shared__ __align__(16) float s_hbuf[DH];
    __shared__ float s_part[8][128];
    __shared__ __align__(16) float s_inT[DH * 36];    // 73728 B
    __shared__ __align__(16) float s_wt[32 * 516];    // 66048 B

    const int bIdx = blockIdx.x;
    const int m8 = bIdx & 7;
    const int tid = threadIdx.x;

    if (bIdx < 32 && m8 < 2) {
        // ================= scan role =================
        const int L = m8;
        const int b = bIdx >> 3;          // slice 0..3, owns cols [128b,128b+128)
        const int c = tid >> 7;           // input chunk 0..7 (64 inputs)
        const int o = tid & 127;
        const int og = (b << 7) + o;

        const float* Wh  = L ? Wh1 : Wh0;
        const float* bhv = L ? bh1 : bh0;
        const float* h0v = L ? h01 : h00;
        float* Hful      = L ? H1r : H0r;
        const float* Xp  = L ? H0r : H1r;   // Xp1 overlays H0, Xp0 overlays H1
        uint32_t* ring         = &g_ring[L][0][0];
        uint32_t* flagXp       = &g_flagXp[L][0];

        float wh[64];
        #pragma unroll
        for (int j = 0; j < 64; ++j)
            wh[j] = Wh[(size_t)((c << 6) + j) * DH + og];
        const float bias = bhv[og];

        // role layout (reducers+copiers live INSIDE the self chunk range
        // [b<<8, b<<8+256) so they are phase-1 threads and never pollers):
        //   reducers: first 128 of self range (own column og)
        //   copiers : second 128 of self range (write Hful row t-1, top of iter t)
        // pollers: 384 threads starting right after the self range, one remote
        // column each.
        const int rofs = tid - (b << 8);
        const bool isRed  = ((unsigned)rofs < 128u);
        const bool isCopy = ((unsigned)(rofs - 128) < 128u);
        const int ptid = (tid + 1024 - ((b << 8) + 256)) & 1023;
        const bool isPoll = ptid < 384;
        const int pcol = (ptid < (b << 7)) ? ptid : ptid + 128;
        const bool isSelf = (c >> 1) == b;

        if (tid < DH) s_hbuf[tid] = h0v[tid];

        // xp double-buffer: entering iter t, xp_pend (issued at iter t-1) = Xp[t].
        float xp_cur = 0.f, xp_pend = 0.f;
        int curCh = -1;
        if (isRed) {
            while (__hip_atomic_load(&flagXp[0], __ATOMIC_ACQUIRE,
                                     __HIP_MEMORY_SCOPE_AGENT) != 1u)
                __builtin_amdgcn_s_sleep(1);
            curCh = 0;
            xp_pend = aloadf(&Xp[og]);           // Xp[0]
        }
        __syncthreads();

        for (int t = 0; t < TT; ++t) {
            // -- top-of-iteration work: issued here so the MALL round trips
            //    drain under phase-1 FMAs instead of a dedicated barrier --
            if (isCopy && t > 0)   // Hful row t-1 (s_hbuf stable until this reduce)
                astore((uint32_t*)Hful + (size_t)(t - 1) * DH + og,
                       __float_as_uint(s_hbuf[og]));
            if (isRed) {
                xp_cur = xp_pend;                 // = Xp[t] (issued 1 iter ago)
                if (t + 1 < TT) {
                    const int ch = (t + 1) >> 5;
                    if (ch != curCh) {
                        while (__hip_atomic_load(&flagXp[ch], __ATOMIC_ACQUIRE,
                                                 __HIP_MEMORY_SCOPE_AGENT) != 1u) {}
                        curCh = ch;
                    }
                    xp_pend = aloadf(&Xp[(size_t)(t + 1) * DH + og]);
                }
            }
            if (t > 0 && isPoll) {
                const uint32_t par = (uint32_t)((t - 1) >> 4) & 1u;
                const uint32_t* p = &ring[(((t - 1) & 15) << 9) + pcol];
                uint32_t v;
                do { v = aload(p); } while ((v >> 31) != par);
                s_hbuf[pcol] = __uint_as_float(v & 0x7fffffffu);
            }
            float acc = 0.f;
            if (isSelf | (t == 0)) {       // phase 1: overlaps the round trip
                const float4* h4 = (const float4*)&s_hbuf[c << 6];
                #pragma unroll
                for (int j4 = 0; j4 < 16; ++j4) {
                    float4 hv = h4[j4];
                    acc += wh[4*j4+0]*hv.x + wh[4*j4+1]*hv.y
                         + wh[4*j4+2]*hv.z + wh[4*j4+3]*hv.w;
                }
                s_part[c][o] = acc;
            }
            __syncthreads();               // remote h staged
            if (!(isSelf | (t == 0))) {    // phase 2: remote-dependent FMAs
                const float4* h4 = (const float4*)&s_hbuf[c << 6];
                #pragma unroll
                for (int j4 = 0; j4 < 16; ++j4) {
                    float4 hv = h4[j4];
                    acc += wh[4*j4+0]*hv.x + wh[4*j4+1]*hv.y
                         + wh[4*j4+2]*hv.z + wh[4*j4+3]*hv.w;
                }
                s_part[c][o] = acc;
            }
            __syncthreads();               // partials ready
            if (isRed) {
                float v = bias + xp_cur;
                #pragma unroll
                for (int cc = 0; cc < 8; ++cc) v += s_part[cc][o];
                v = fmaxf(v, 0.f);
                const uint32_t hb = __float_as_uint(v);
                // ring store is now the ONLY store before the loop-end barrier:
                // its drain is the sole MALL latency on the critical path here
                astore(&ring[((t & 15) << 9) + og],
                       hb | (((uint32_t)(t >> 4) & 1u) << 31));
                s_hbuf[og] = v;
            }
            __syncthreads();               // hbuf self-slice ready for next step
        }
        // epilogue: last Hful row (copiers lag by one step inside the loop)
        if (isCopy)
            astore((uint32_t*)Hful + (size_t)(TT - 1) * DH + og,
                   __float_as_uint(s_hbuf[og]));
    } else {
        // ================= projector role =================
        const int pi = (bIdx < 32) ? (((bIdx >> 3) * 6) + (m8 - 2))
                                   : (24 + (bIdx - 32));      // 0..55
        for (int cc = pi; cc < NCHUNK; cc += NPROJ) {
            proj_chunk(Wx0, X,   0, H1r /*Xp0*/, &g_flagXp[0][cc], cc * CROWS, s_inT, s_wt);
            proj_chunk(Wx1, H0r, 1, H0r /*Xp1*/, &g_flagXp[1][cc], cc * CROWS, s_inT, s_wt);
        }
    }
}

// out[t][k] = dot(H1[t], W_log[k]) + b_log[k].  Block = 8 timesteps x 128 k.
__global__ __launch_bounds__(128, 1)
void logits_kernel(const float* __restrict__ H1, const float* __restrict__ Wl,
                   const float* __restrict__ bl, float* __restrict__ out)
{
    const int t0 = blockIdx.x * 8;
    const int k = threadIdx.x;

    __shared__ __align__(16) float hs[8 * DH];
    for (int idx = k; idx < 8 * DH / 4; idx += 128)
        ((float4*)hs)[idx] = ((const float4*)&H1[(size_t)t0 * DH])[idx];
    __syncthreads();

    float acc[8];
    const float bk = bl[k];
    #pragma unroll
    for (int r = 0; r < 8; ++r) acc[r] = bk;

    const float4* w4 = (const float4*)&Wl[(size_t)k * DH];
    for (int j = 0; j < DH / 4; ++j) {
        float4 w = w4[j];
        #pragma unroll
        for (int r = 0; r < 8; ++r) {
            float4 h = ((const float4*)&hs[r * DH])[j];
            acc[r] += w.x * h.x + w.y * h.y + w.z * h.z + w.w * h.w;
        }
    }
    #pragma unroll
    for (int r = 0; r < 8; ++r) out[(size_t)(t0 + r) * KK + k] = acc[r];
}

extern "C" void kernel_launch(void* const* d_in, const int* in_sizes, int n_in,
                              void* d_out, int out_size, void* d_ws, size_t ws_size,
                              hipStream_t stream)
{
    const float* X   = (const float*)d_in[0];
    const float* Wx0 = (const float*)d_in[1];
    const float* Wh0 = (const float*)d_in[2];
    const float* bh0 = (const float*)d_in[3];
    const float* h00 = (const float*)d_in[4];
    const float* Wx1 = (const float*)d_in[5];
    const float* Wh1 = (const float*)d_in[6];
    const float* bh1 = (const float*)d_in[7];
    const float* h01 = (const float*)d_in[8];
    const float* Wl  = (const float*)d_in[9];
    const float* bl  = (const float*)d_in[10];
    float* out = (float*)d_out;

    float* H0r = (float*)d_ws;                  // H0, later overlaid by Xp1
    float* H1r = H0r + (size_t)TT * DH;         // Xp0 first, then H1

    // H0 region must start at sentinel (harness poisons d_ws; this is defensive)
    hipMemsetAsync(d_ws, 0xAA, (size_t)TT * DH * sizeof(float), stream);
    hipLaunchKernelGGL(init_kernel, dim3(1), dim3(1024), 0, stream);
    hipLaunchKernelGGL(fused, dim3(64), dim3(1024), 0, stream,
                       X, Wx0, Wh0, bh0, h00, Wx1, Wh1, bh1, h01, H0r, H1r);
    hipLaunchKernelGGL(logits_kernel, dim3(TT / 8), dim3(128), 0, stream,
                       H1r, Wl, bl, out);
}

// Round 3
// 21510.847 us; speedup vs baseline: 1.1511x; 1.1511x over previous
//
#include <hip/hip_runtime.h>
#include <stdint.h>

#define TT 16384
#define DH 512
#define KK 128
#define SENT 0xAAAAAAAAu
#define CROWS 32
#define NCHUNK (TT / CROWS)   // 512
#define NPROJ 56
#define RSLOT 16

// Small cross-block state lives in device globals (ws budget stays at the
// proven 2*TT*DH floats). Re-initialized by init_kernel every launch.
__device__ uint32_t g_ring[2][RSLOT][DH];   // parity-tagged h exchange rings
__device__ uint32_t g_flagXp[2][NCHUNK];    // Xp chunk-ready flags (1 = ready)
__device__ uint32_t g_flagH[4][NCHUNK];     // H0 chunk-ready flags, per scan-0 block

static __device__ __forceinline__ uint32_t aload(const uint32_t* p) {
    return __hip_atomic_load(p, __ATOMIC_RELAXED, __HIP_MEMORY_SCOPE_AGENT);
}
static __device__ __forceinline__ void astore(uint32_t* p, uint32_t v) {
    __hip_atomic_store(p, v, __ATOMIC_RELAXED, __HIP_MEMORY_SCOPE_AGENT);
}
static __device__ __forceinline__ float aloadf(const float* p) {
    return __uint_as_float(aload((const uint32_t*)p));
}

__global__ void init_kernel() {
    const int tid = threadIdx.x;
    uint32_t* r = &g_ring[0][0][0];
    for (int i = tid; i < 2 * RSLOT * DH; i += 1024) r[i] = SENT;  // sign bit 1
    uint32_t* f = &g_flagXp[0][0];
    for (int i = tid; i < 2 * NCHUNK; i += 1024) f[i] = SENT;      // != 1
    uint32_t* g = &g_flagH[0][0];
    for (int i = tid; i < 4 * NCHUNK; i += 1024) g[i] = 0u;        // != 1
}

// ---------------- projector: 32-row chunk GEMM  dst = src @ W  ----------------
// srcMode 0: plain loads (X, pre-written).  srcMode 1: chunk-flag wait (4
// threads poll g_flagH with backoff), then ONE agent load per word — no
// per-word spinning.  This removes ~700 GB/s of MALL spin traffic that was
// queue-delaying the scan's critical ring stores/polls.  In-place overwrite of
// H0 by Xp1 stays safe: the chunk is fully staged to LDS (barrier) before any
// store.
static __device__ void proj_chunk(const float* __restrict__ W,
                                  const float* __restrict__ src, int srcMode,
                                  float* __restrict__ dst, uint32_t* flag, int t0,
                                  float* inT /* [DH][36] */, float* wt /* [32][516] */)
{
    const int tid = threadIdx.x;
    if (srcMode == 1) {
        if (tid < 4) {
            while (__hip_atomic_load(&g_flagH[tid][t0 >> 5], __ATOMIC_ACQUIRE,
                                     __HIP_MEMORY_SCOPE_AGENT) != 1u)
                __builtin_amdgcn_s_sleep(8);
        }
        __syncthreads();
    }
    // stage input chunk transposed: inT[k][row]
    #pragma unroll
    for (int i = 0; i < 16; ++i) {
        int idx = tid + 1024 * i;            // 0..16383
        int row = idx >> 9;
        int col = idx & 511;
        float v = (srcMode == 0) ? src[(size_t)t0 * DH + idx]
                                 : aloadf(&src[(size_t)t0 * DH + idx]);
        inT[col * 36 + row] = v;
    }
    __syncthreads();

    const int rg = (tid >> 7) & 7;   // row group: rows 4rg..4rg+3
    const int cg = tid & 127;        // col group: cols 4cg..4cg+3
    float acc[4][4] = {{0.f}};

    for (int kt = 0; kt < 16; ++kt) {
        const int k0 = kt * 32;
        #pragma unroll
        for (int i = 0; i < 4; ++i) {                  // stage 32x512 W tile
            int f4 = tid + 1024 * i;                   // 0..4095 float4s
            int wr = f4 >> 7;
            int wc = (f4 & 127) << 2;
            *(float4*)&wt[wr * 516 + wc] =
                *(const float4*)&W[(size_t)(k0 + wr) * DH + wc];
        }
        __syncthreads();
        #pragma unroll 8
        for (int kk = 0; kk < 32; ++kk) {
            float4 a = *(const float4*)&inT[(k0 + kk) * 36 + (rg << 2)];
            float4 w = *(const float4*)&wt[kk * 516 + (cg << 2)];
            acc[0][0] += a.x * w.x; acc[0][1] += a.x * w.y; acc[0][2] += a.x * w.z; acc[0][3] += a.x * w.w;
            acc[1][0] += a.y * w.x; acc[1][1] += a.y * w.y; acc[1][2] += a.y * w.z; acc[1][3] += a.y * w.w;
            acc[2][0] += a.z * w.x; acc[2][1] += a.z * w.y; acc[2][2] += a.z * w.z; acc[2][3] += a.z * w.w;
            acc[3][0] += a.w * w.x; acc[3][1] += a.w * w.y; acc[3][2] += a.w * w.z; acc[3][3] += a.w * w.w;
        }
        __syncthreads();
    }
    #pragma unroll
    for (int i = 0; i < 4; ++i)
        #pragma unroll
        for (int j = 0; j < 4; ++j)
            astore((uint32_t*)&dst[(size_t)(t0 + (rg << 2) + i) * DH + (cg << 2) + j],
                   __float_as_uint(acc[i][j]));
    __threadfence();
    __syncthreads();
    if (tid == 0)
        __hip_atomic_store(flag, 1u, __ATOMIC_RELEASE, __HIP_MEMORY_SCOPE_AGENT);
}

// ---------------- fused persistent kernel ----------------
// grid = 64 x 1024.  Blocks with (b<32 && b%8<2): scan role, layer=b%8, slice=b>>3
// (b%8 swizzle: layer-0 scan blocks land on one XCD if dispatch is round-robin —
// perf heuristic only).  All other blocks: projectors for Xp0/Xp1.
// Scan structure is the proven round-0 baseline (all vmem drains consolidated
// at the single loop-end barrier — round-2 showed splitting them across two
// barriers costs one extra MALL round trip per step).  Only addition: a
// publisher thread on scan-0 posts g_flagH once per 32 steps.
__global__ __launch_bounds__(1024, 1)
void fused(const float* __restrict__ X,
           const float* __restrict__ Wx0, const float* __restrict__ Wh0,
           const float* __restrict__ bh0, const float* __restrict__ h00,
           const float* __restrict__ Wx1, const float* __restrict__ Wh1,
           const float* __restrict__ bh1, const float* __restrict__ h01,
           float* H0r, float* H1r)
{
    __shared__ __align__(16) float s_hbuf[DH];
    __shared__ float s_part[8][128];
    __shared__ __align__(16) float s_inT[DH * 36];    // 73728 B
    __shared__ __align__(16) float s_wt[32 * 516];    // 66048 B

    const int bIdx = blockIdx.x;
    const int m8 = bIdx & 7;
    const int tid = threadIdx.x;

    if (bIdx < 32 && m8 < 2) {
        // ================= scan role =================
        const int L = m8;
        const int b = bIdx >> 3;          // slice 0..3, owns cols [128b,128b+128)
        const int c = tid >> 7;           // input chunk 0..7 (64 inputs)
        const int o = tid & 127;
        const int og = (b << 7) + o;

        const float* Wh  = L ? Wh1 : Wh0;
        const float* bhv = L ? bh1 : bh0;
        const float* h0v = L ? h01 : h00;
        float* Hful      = L ? H1r : H0r;
        const float* Xp  = L ? H0r : H1r;   // Xp1 overlays H0, Xp0 overlays H1
        uint32_t* ring         = &g_ring[L][0][0];
        uint32_t* flagXp       = &g_flagXp[L][0];

        float wh[64];
        #pragma unroll
        for (int j = 0; j < 64; ++j)
            wh[j] = Wh[(size_t)((c << 6) + j) * DH + og];
        const float bias = bhv[og];

        // pollers: 384 threads outside the self range, one remote col each
        const int ptid = (tid + 1024 - ((b << 8) + 256)) & 1023;
        const bool isPoll = ptid < 384;
        const int pcol = (ptid < (b << 7)) ? ptid : ptid + 128;
        const bool isSelf = (c >> 1) == b;
        const bool isRed = tid < 128;     // reducer threads, o == tid
        // publisher: one thread per scan-0 block, never a poller, never a
        // reducer (tid = b*256+128 is in the self range's second half).
        const bool isPub = (L == 0) && (tid == ((b << 8) + 128));

        if (tid < DH) s_hbuf[tid] = h0v[tid];

        float xp_next = 0.f;
        int curCh = -1;
        if (isRed) {
            while (__hip_atomic_load(&flagXp[0], __ATOMIC_ACQUIRE,
                                     __HIP_MEMORY_SCOPE_AGENT) != 1u)
                __builtin_amdgcn_s_sleep(1);
            curCh = 0;
            xp_next = aloadf(&Xp[og]);
        }
        __syncthreads();

        for (int t = 0; t < TT; ++t) {
            // publish chunk (t/32 - 1): its Hful rows all drained at the
            // loop-end barrier of step t-1 (store ordered by that barrier).
            // Off the critical path: 1 store / 32 steps by one thread.
            if (isPub && t > 0 && (t & 31) == 0)
                astore(&g_flagH[b][(t >> 5) - 1], 1u);
            if (t > 0 && isPoll) {
                const uint32_t par = (uint32_t)((t - 1) >> 4) & 1u;
                const uint32_t* p = &ring[(((t - 1) & 15) << 9) + pcol];
                uint32_t v;
                do { v = aload(p); } while ((v >> 31) != par);
                s_hbuf[pcol] = __uint_as_float(v & 0x7fffffffu);
            }
            float acc = 0.f;
            if (isSelf | (t == 0)) {       // phase 1: overlaps the round trip
                const float4* h4 = (const float4*)&s_hbuf[c << 6];
                #pragma unroll
                for (int j4 = 0; j4 < 16; ++j4) {
                    float4 hv = h4[j4];
                    acc += wh[4*j4+0]*hv.x + wh[4*j4+1]*hv.y
                         + wh[4*j4+2]*hv.z + wh[4*j4+3]*hv.w;
                }
                s_part[c][o] = acc;
            }
            __syncthreads();               // remote h staged
            if (!(isSelf | (t == 0))) {    // phase 2: remote-dependent FMAs
                const float4* h4 = (const float4*)&s_hbuf[c << 6];
                #pragma unroll
                for (int j4 = 0; j4 < 16; ++j4) {
                    float4 hv = h4[j4];
                    acc += wh[4*j4+0]*hv.x + wh[4*j4+1]*hv.y
                         + wh[4*j4+2]*hv.z + wh[4*j4+3]*hv.w;
                }
                s_part[c][o] = acc;
            }
            __syncthreads();               // partials ready
            if (isRed) {
                float v = bias + xp_next;
                #pragma unroll
                for (int cc = 0; cc < 8; ++cc) v += s_part[cc][o];
                v = fmaxf(v, 0.f);
                const uint32_t hb = __float_as_uint(v);
                // ring store FIRST: other blocks' pollers depend on it
                astore(&ring[((t & 15) << 9) + og],
                       hb | (((uint32_t)(t >> 4) & 1u) << 31));
                astore((uint32_t*)Hful + (size_t)t * DH + og, hb);
                s_hbuf[og] = v;
                if (t + 1 < TT) {          // prefetch next xp (off critical path)
                    const int ch = (t + 1) >> 5;
                    if (ch != curCh) {
                        while (__hip_atomic_load(&flagXp[ch], __ATOMIC_ACQUIRE,
                                                 __HIP_MEMORY_SCOPE_AGENT) != 1u) {}
                        curCh = ch;
                    }
                    xp_next = aloadf(&Xp[(size_t)(t + 1) * DH + og]);
                }
            }
            __syncthreads();               // hbuf self-slice ready for next step
        }
        // final chunk flag: rows ..16383 drained at the last loop-end barrier
        if (isPub)
            astore(&g_flagH[b][NCHUNK - 1], 1u);
    } else {
        // ================= projector role =================
        const int pi = (bIdx < 32) ? (((bIdx >> 3) * 6) + (m8 - 2))
                                   : (24 + (bIdx - 32));      // 0..55
        for (int cc = pi; cc < NCHUNK; cc += NPROJ) {
            proj_chunk(Wx0, X,   0, H1r /*Xp0*/, &g_flagXp[0][cc], cc * CROWS, s_inT, s_wt);
            proj_chunk(Wx1, H0r, 1, H0r /*Xp1*/, &g_flagXp[1][cc], cc * CROWS, s_inT, s_wt);
        }
    }
}

// out[t][k] = dot(H1[t], W_log[k]) + b_log[k].  Block = 8 timesteps x 128 k.
__global__ __launch_bounds__(128, 1)
void logits_kernel(const float* __restrict__ H1, const float* __restrict__ Wl,
                   const float* __restrict__ bl, float* __restrict__ out)
{
    const int t0 = blockIdx.x * 8;
    const int k = threadIdx.x;

    __shared__ __align__(16) float hs[8 * DH];
    for (int idx = k; idx < 8 * DH / 4; idx += 128)
        ((float4*)hs)[idx] = ((const float4*)&H1[(size_t)t0 * DH])[idx];
    __syncthreads();

    float acc[8];
    const float bk = bl[k];
    #pragma unroll
    for (int r = 0; r < 8; ++r) acc[r] = bk;

    const float4* w4 = (const float4*)&Wl[(size_t)k * DH];
    for (int j = 0; j < DH / 4; ++j) {
        float4 w = w4[j];
        #pragma unroll
        for (int r = 0; r < 8; ++r) {
            float4 h = ((const float4*)&hs[r * DH])[j];
            acc[r] += w.x * h.x + w.y * h.y + w.z * h.z + w.w * h.w;
        }
    }
    #pragma unroll
    for (int r = 0; r < 8; ++r) out[(size_t)(t0 + r) * KK + k] = acc[r];
}

extern "C" void kernel_launch(void* const* d_in, const int* in_sizes, int n_in,
                              void* d_out, int out_size, void* d_ws, size_t ws_size,
                              hipStream_t stream)
{
    const float* X   = (const float*)d_in[0];
    const float* Wx0 = (const float*)d_in[1];
    const float* Wh0 = (const float*)d_in[2];
    const float* bh0 = (const float*)d_in[3];
    const float* h00 = (const float*)d_in[4];
    const float* Wx1 = (const float*)d_in[5];
    const float* Wh1 = (const float*)d_in[6];
    const float* bh1 = (const float*)d_in[7];
    const float* h01 = (const float*)d_in[8];
    const float* Wl  = (const float*)d_in[9];
    const float* bl  = (const float*)d_in[10];
    float* out = (float*)d_out;

    float* H0r = (float*)d_ws;                  // H0, later overlaid by Xp1
    float* H1r = H0r + (size_t)TT * DH;         // Xp0 first, then H1

    // H0 region must start at sentinel (harness poisons d_ws; this is defensive)
    hipMemsetAsync(d_ws, 0xAA, (size_t)TT * DH * sizeof(float), stream);
    hipLaunchKernelGGL(init_kernel, dim3(1), dim3(1024), 0, stream);
    hipLaunchKernelGGL(fused, dim3(64), dim3(1024), 0, stream,
                       X, Wx0, Wh0, bh0, h00, Wx1, Wh1, bh1, h01, H0r, H1r);
    hipLaunchKernelGGL(logits_kernel, dim3(TT / 8), dim3(128), 0, stream,
                       H1r, Wl, bl, out);
}

// Round 4
// 20190.259 us; speedup vs baseline: 1.2264x; 1.0654x over previous
//
#include <hip/hip_runtime.h>
#include <stdint.h>

#define TT 16384
#define DH 512
#define KK 128
#define SENT 0xAAAAAAAAu
#define CROWS 32
#define NCHUNK (TT / CROWS)   // 512
#define NPROJ 56
#define RSLOT 16

// LDS-only barrier: orders LDS (lgkmcnt) but does NOT drain vmcnt — the
// loop-end __syncthreads was costing a full MALL RTT (~1100 cyc/step) waiting
// for ring/Hful store ACKS and the xp prefetch return that no thread in this
// block consumes across the barrier.  All in-block cross-thread data is LDS;
// cross-block data uses per-word parity/sentinel protocols (order-free).
#define BARRIER_LDS() do { \
    asm volatile("s_waitcnt lgkmcnt(0)" ::: "memory"); \
    __builtin_amdgcn_s_barrier(); \
} while (0)

// Small cross-block state lives in device globals (ws budget stays at the
// proven 2*TT*DH floats). Re-initialized by init_kernel every launch.
__device__ uint32_t g_ring[2][RSLOT][DH];   // parity-tagged h exchange rings
__device__ uint32_t g_flagXp[2][NCHUNK];    // Xp chunk-ready flags (1 = ready)

static __device__ __forceinline__ uint32_t aload(const uint32_t* p) {
    return __hip_atomic_load(p, __ATOMIC_RELAXED, __HIP_MEMORY_SCOPE_AGENT);
}
static __device__ __forceinline__ void astore(uint32_t* p, uint32_t v) {
    __hip_atomic_store(p, v, __ATOMIC_RELAXED, __HIP_MEMORY_SCOPE_AGENT);
}
static __device__ __forceinline__ float aloadf(const float* p) {
    return __uint_as_float(aload((const uint32_t*)p));
}

__global__ void init_kernel() {
    const int tid = threadIdx.x;
    uint32_t* r = &g_ring[0][0][0];
    for (int i = tid; i < 2 * RSLOT * DH; i += 1024) r[i] = SENT;  // sign bit 1
    uint32_t* f = &g_flagXp[0][0];
    for (int i = tid; i < 2 * NCHUNK; i += 1024) f[i] = SENT;      // != 1
}

// ---------------- projector: 32-row chunk GEMM  dst = src @ W  ----------------
// srcMode 0: plain loads (X, pre-written).  srcMode 1: per-word sentinel poll
// (H0, written live by scan-0; in-place overwrite is safe: sole consumer is us,
// and the chunk is fully staged to LDS before any store).  Round-3 lesson:
// chunk-granular flags DELAY staging (can't stream behind the producer) and
// the spin traffic was never the scan's bottleneck — per-word is better.
static __device__ void proj_chunk(const float* __restrict__ W,
                                  const float* __restrict__ src, int srcMode,
                                  float* __restrict__ dst, uint32_t* flag, int t0,
                                  float* inT /* [DH][36] */, float* wt /* [32][516] */)
{
    const int tid = threadIdx.x;
    // stage input chunk transposed: inT[k][row]
    #pragma unroll
    for (int i = 0; i < 16; ++i) {
        int idx = tid + 1024 * i;            // 0..16383
        int row = idx >> 9;
        int col = idx & 511;
        float v;
        if (srcMode == 0) {
            v = src[(size_t)t0 * DH + idx];
        } else {
            const uint32_t* p = (const uint32_t*)src + (size_t)t0 * DH + idx;
            uint32_t u;
            while ((u = aload(p)) == SENT) __builtin_amdgcn_s_sleep(1);
            v = __uint_as_float(u);
        }
        inT[col * 36 + row] = v;
    }
    __syncthreads();

    const int rg = (tid >> 7) & 7;   // row group: rows 4rg..4rg+3
    const int cg = tid & 127;        // col group: cols 4cg..4cg+3
    float acc[4][4] = {{0.f}};

    for (int kt = 0; kt < 16; ++kt) {
        const int k0 = kt * 32;
        #pragma unroll
        for (int i = 0; i < 4; ++i) {                  // stage 32x512 W tile
            int f4 = tid + 1024 * i;                   // 0..4095 float4s
            int wr = f4 >> 7;
            int wc = (f4 & 127) << 2;
            *(float4*)&wt[wr * 516 + wc] =
                *(const float4*)&W[(size_t)(k0 + wr) * DH + wc];
        }
        __syncthreads();
        #pragma unroll 8
        for (int kk = 0; kk < 32; ++kk) {
            float4 a = *(const float4*)&inT[(k0 + kk) * 36 + (rg << 2)];
            float4 w = *(const float4*)&wt[kk * 516 + (cg << 2)];
            acc[0][0] += a.x * w.x; acc[0][1] += a.x * w.y; acc[0][2] += a.x * w.z; acc[0][3] += a.x * w.w;
            acc[1][0] += a.y * w.x; acc[1][1] += a.y * w.y; acc[1][2] += a.y * w.z; acc[1][3] += a.y * w.w;
            acc[2][0] += a.z * w.x; acc[2][1] += a.z * w.y; acc[2][2] += a.z * w.z; acc[2][3] += a.z * w.w;
            acc[3][0] += a.w * w.x; acc[3][1] += a.w * w.y; acc[3][2] += a.w * w.z; acc[3][3] += a.w * w.w;
        }
        __syncthreads();
    }
    #pragma unroll
    for (int i = 0; i < 4; ++i)
        #pragma unroll
        for (int j = 0; j < 4; ++j)
            astore((uint32_t*)&dst[(size_t)(t0 + (rg << 2) + i) * DH + (cg << 2) + j],
                   __float_as_uint(acc[i][j]));
    __threadfence();
    __syncthreads();
    if (tid == 0)
        __hip_atomic_store(flag, 1u, __ATOMIC_RELEASE, __HIP_MEMORY_SCOPE_AGENT);
}

// ---------------- fused persistent kernel ----------------
// grid = 64 x 1024.  Blocks with (b<32 && b%8<2): scan role, layer=b%8, slice=b>>3
// (b%8 swizzle: layer-0 scan blocks land on one XCD if dispatch is round-robin —
// perf heuristic only).  All other blocks: projectors for Xp0/Xp1.
// Scan structure = proven round-0 baseline; the ONLY change is the three
// in-loop barriers: LDS-ordered raw s_barrier instead of __syncthreads, so
// ring/Hful store acks and the xp prefetch RTT ride across steps instead of
// being drained every loop-end barrier.
__global__ __launch_bounds__(1024, 1)
void fused(const float* __restrict__ X,
           const float* __restrict__ Wx0, const float* __restrict__ Wh0,
           const float* __restrict__ bh0, const float* __restrict__ h00,
           const float* __restrict__ Wx1, const float* __restrict__ Wh1,
           const float* __restrict__ bh1, const float* __restrict__ h01,
           float* H0r, float* H1r)
{
    __shared__ __align__(16) float s_hbuf[DH];
    __shared__ float s_part[8][128];
    __shared__ __align__(16) float s_inT[DH * 36];    // 73728 B
    __shared__ __align__(16) float s_wt[32 * 516];    // 66048 B

    const int bIdx = blockIdx.x;
    const int m8 = bIdx & 7;
    const int tid = threadIdx.x;

    if (bIdx < 32 && m8 < 2) {
        // ================= scan role =================
        const int L = m8;
        const int b = bIdx >> 3;          // slice 0..3, owns cols [128b,128b+128)
        const int c = tid >> 7;           // input chunk 0..7 (64 inputs)
        const int o = tid & 127;
        const int og = (b << 7) + o;

        const float* Wh  = L ? Wh1 : Wh0;
        const float* bhv = L ? bh1 : bh0;
        const float* h0v = L ? h01 : h00;
        float* Hful      = L ? H1r : H0r;
        const float* Xp  = L ? H0r : H1r;   // Xp1 overlays H0, Xp0 overlays H1
        uint32_t* ring         = &g_ring[L][0][0];
        uint32_t* flagXp       = &g_flagXp[L][0];

        float wh[64];
        #pragma unroll
        for (int j = 0; j < 64; ++j)
            wh[j] = Wh[(size_t)((c << 6) + j) * DH + og];
        const float bias = bhv[og];

        // pollers: 384 threads outside the self range, one remote col each
        const int ptid = (tid + 1024 - ((b << 8) + 256)) & 1023;
        const bool isPoll = ptid < 384;
        const int pcol = (ptid < (b << 7)) ? ptid : ptid + 128;
        const bool isSelf = (c >> 1) == b;
        const bool isRed = tid < 128;     // reducer threads, o == tid

        if (tid < DH) s_hbuf[tid] = h0v[tid];

        float xp_next = 0.f;
        int curCh = -1;
        if (isRed) {
            while (__hip_atomic_load(&flagXp[0], __ATOMIC_ACQUIRE,
                                     __HIP_MEMORY_SCOPE_AGENT) != 1u)
                __builtin_amdgcn_s_sleep(1);
            curCh = 0;
            xp_next = aloadf(&Xp[og]);
        }
        __syncthreads();

        for (int t = 0; t < TT; ++t) {
            if (t > 0 && isPoll) {
                const uint32_t par = (uint32_t)((t - 1) >> 4) & 1u;
                const uint32_t* p = &ring[(((t - 1) & 15) << 9) + pcol];
                uint32_t v;
                do { v = aload(p); } while ((v >> 31) != par);
                s_hbuf[pcol] = __uint_as_float(v & 0x7fffffffu);
            }
            float acc = 0.f;
            if (isSelf | (t == 0)) {       // phase 1: overlaps the round trip
                const float4* h4 = (const float4*)&s_hbuf[c << 6];
                #pragma unroll
                for (int j4 = 0; j4 < 16; ++j4) {
                    float4 hv = h4[j4];
                    acc += wh[4*j4+0]*hv.x + wh[4*j4+1]*hv.y
                         + wh[4*j4+2]*hv.z + wh[4*j4+3]*hv.w;
                }
                s_part[c][o] = acc;
            }
            BARRIER_LDS();                 // remote h staged
            if (!(isSelf | (t == 0))) {    // phase 2: remote-dependent FMAs
                const float4* h4 = (const float4*)&s_hbuf[c << 6];
                #pragma unroll
                for (int j4 = 0; j4 < 16; ++j4) {
                    float4 hv = h4[j4];
                    acc += wh[4*j4+0]*hv.x + wh[4*j4+1]*hv.y
                         + wh[4*j4+2]*hv.z + wh[4*j4+3]*hv.w;
                }
                s_part[c][o] = acc;
            }
            BARRIER_LDS();                 // partials ready
            if (isRed) {
                float v = bias + xp_next;
                #pragma unroll
                for (int cc = 0; cc < 8; ++cc) v += s_part[cc][o];
                v = fmaxf(v, 0.f);
                const uint32_t hb = __float_as_uint(v);
                // ring store FIRST: other blocks' pollers depend on it
                astore(&ring[((t & 15) << 9) + og],
                       hb | (((uint32_t)(t >> 4) & 1u) << 31));
                astore((uint32_t*)Hful + (size_t)t * DH + og, hb);
                s_hbuf[og] = v;
                if (t + 1 < TT) {          // prefetch next xp (off critical path)
                    const int ch = (t + 1) >> 5;
                    if (ch != curCh) {
                        while (__hip_atomic_load(&flagXp[ch], __ATOMIC_ACQUIRE,
                                                 __HIP_MEMORY_SCOPE_AGENT) != 1u) {}
                        curCh = ch;
                    }
                    xp_next = aloadf(&Xp[(size_t)(t + 1) * DH + og]);
                }
            }
            BARRIER_LDS();                 // hbuf self-slice ready for next step
        }
    } else {
        // ================= projector role =================
        const int pi = (bIdx < 32) ? (((bIdx >> 3) * 6) + (m8 - 2))
                                   : (24 + (bIdx - 32));      // 0..55
        for (int cc = pi; cc < NCHUNK; cc += NPROJ) {
            proj_chunk(Wx0, X,   0, H1r /*Xp0*/, &g_flagXp[0][cc], cc * CROWS, s_inT, s_wt);
            proj_chunk(Wx1, H0r, 1, H0r /*Xp1*/, &g_flagXp[1][cc], cc * CROWS, s_inT, s_wt);
        }
    }
}

// out[t][k] = dot(H1[t], W_log[k]) + b_log[k].  Block = 8 timesteps x 128 k.
__global__ __launch_bounds__(128, 1)
void logits_kernel(const float* __restrict__ H1, const float* __restrict__ Wl,
                   const float* __restrict__ bl, float* __restrict__ out)
{
    const int t0 = blockIdx.x * 8;
    const int k = threadIdx.x;

    __shared__ __align__(16) float hs[8 * DH];
    for (int idx = k; idx < 8 * DH / 4; idx += 128)
        ((float4*)hs)[idx] = ((const float4*)&H1[(size_t)t0 * DH])[idx];
    __syncthreads();

    float acc[8];
    const float bk = bl[k];
    #pragma unroll
    for (int r = 0; r < 8; ++r) acc[r] = bk;

    const float4* w4 = (const float4*)&Wl[(size_t)k * DH];
    for (int j = 0; j < DH / 4; ++j) {
        float4 w = w4[j];
        #pragma unroll
        for (int r = 0; r < 8; ++r) {
            float4 h = ((const float4*)&hs[r * DH])[j];
            acc[r] += w.x * h.x + w.y * h.y + w.z * h.z + w.w * h.w;
        }
    }
    #pragma unroll
    for (int r = 0; r < 8; ++r) out[(size_t)(t0 + r) * KK + k] = acc[r];
}

extern "C" void kernel_launch(void* const* d_in, const int* in_sizes, int n_in,
                              void* d_out, int out_size, void* d_ws, size_t ws_size,
                              hipStream_t stream)
{
    const float* X   = (const float*)d_in[0];
    const float* Wx0 = (const float*)d_in[1];
    const float* Wh0 = (const float*)d_in[2];
    const float* bh0 = (const float*)d_in[3];
    const float* h00 = (const float*)d_in[4];
    const float* Wx1 = (const float*)d_in[5];
    const float* Wh1 = (const float*)d_in[6];
    const float* bh1 = (const float*)d_in[7];
    const float* h01 = (const float*)d_in[8];
    const float* Wl  = (const float*)d_in[9];
    const float* bl  = (const float*)d_in[10];
    float* out = (float*)d_out;

    float* H0r = (float*)d_ws;                  // H0, later overlaid by Xp1
    float* H1r = H0r + (size_t)TT * DH;         // Xp0 first, then H1

    // H0 region must start at sentinel (harness poisons d_ws; this is defensive)
    hipMemsetAsync(d_ws, 0xAA, (size_t)TT * DH * sizeof(float), stream);
    hipLaunchKernelGGL(init_kernel, dim3(1), dim3(1024), 0, stream);
    hipLaunchKernelGGL(fused, dim3(64), dim3(1024), 0, stream,
                       X, Wx0, Wh0, bh0, h00, Wx1, Wh1, bh1, h01, H0r, H1r);
    hipLaunchKernelGGL(logits_kernel, dim3(TT / 8), dim3(128), 0, stream,
                       H1r, Wl, bl, out);
}